// Round 12
// baseline (194.074 us; speedup 1.0000x reference)
//
#include <hip/hip_runtime.h>
#include <hip/hip_bf16.h>
#include <stdint.h>

// Round 12 = round 11 resubmitted verbatim (bench infra failed; no data).

typedef unsigned short u16;
typedef unsigned int u32;
typedef __bf16 bf16x8 __attribute__((ext_vector_type(8)));
typedef float f32x4 __attribute__((ext_vector_type(4)));

#define AS1 __attribute__((address_space(1)))
#define AS3 __attribute__((address_space(3)))

// async global->LDS, 16B per lane; LDS dest = wave-uniform base + lane*16.
__device__ __forceinline__ void async16(const u16* g, u16* l) {
  __builtin_amdgcn_global_load_lds((const AS1 uint32_t*)(const void*)g,
                                   (AS3 uint32_t*)l, 16, 0, 0);
}

__device__ __forceinline__ u16 f2bf(float v) {
  union { __hip_bfloat16 b; u16 u; } c; c.b = __float2bfloat16(v); return c.u;
}

__device__ __forceinline__ uint4 pack8(float4 lo, float4 hi) {
  uint4 q;
  q.x = (u32)f2bf(lo.x) | ((u32)f2bf(lo.y) << 16);
  q.y = (u32)f2bf(lo.z) | ((u32)f2bf(lo.w) << 16);
  q.z = (u32)f2bf(hi.x) | ((u32)f2bf(hi.y) << 16);
  q.w = (u32)f2bf(hi.z) | ((u32)f2bf(hi.w) << 16);
  return q;
}

// ---------------- prep: weight transposes (z=0,1) + x convert (z=2,3) -----
__global__ void prep(const float* __restrict__ Wqkv, u16* __restrict__ WqkvT,
                     const float* __restrict__ Wout, u16* __restrict__ WoutT,
                     const float* __restrict__ x, u16* __restrict__ xb) {
  const int z = blockIdx.z;
  if (z >= 2) {                                  // x: fp32 -> bf16 (2M elems per z)
    int bid = blockIdx.y * 32 + blockIdx.x;      // 0..1023
    size_t i = (((size_t)(z - 2) * 1024 + bid) * 256
                + threadIdx.y * 32 + threadIdx.x) * 8;
    float4 lo = *(const float4*)(x + i);
    float4 hi = *(const float4*)(x + i + 4);
    *(uint4*)(xb + i) = pack8(lo, hi);
    return;
  }
  const float* in = z ? Wout : Wqkv;
  u16* out = z ? WoutT : WqkvT;
  __shared__ u16 tile[32][33];
  int tx = threadIdx.x, ty = threadIdx.y;        // block (32,8)
  int c0 = blockIdx.x * 32, r0 = blockIdx.y * 32;
#pragma unroll
  for (int i = 0; i < 32; i += 8)
    tile[ty + i][tx] = f2bf(in[(size_t)(r0 + ty + i) * 1024 + c0 + tx]);
  __syncthreads();
#pragma unroll
  for (int i = 0; i < 32; i += 8)
    out[(size_t)(c0 + ty + i) * 1024 + r0 + tx] = tile[tx][ty + i];
}

// ---------------- GEMM1: w = xb * WqkvT^T, fused Vt epilogue --------------
// 128x64 tile (one head per block) / 256 threads / BK=64 double-buffered:
// async for buf p^1 issued BEFORE compute on buf p -> drain covered.
__launch_bounds__(256)
__global__ void gemm1_fused(const u16* __restrict__ A, const u16* __restrict__ BT,
                            u16* __restrict__ w, const int* __restrict__ mask,
                            u16* __restrict__ Vt) {
  const int K = 1024, N = 1024;
  __shared__ __align__(16) u16 As[2][2][128 * 32];   // 32 KB
  __shared__ __align__(16) u16 Bs[2][2][64 * 32];    // 16 KB
  const int t = threadIdx.x;
  const int lane = t & 63, wave = t >> 6;
  const int m0 = blockIdx.x * 128, n0 = blockIdx.y * 64;
  const int wm = (wave & 1) * 64, wn = (wave >> 1) * 32;
  const int lrow = lane & 15, quad = lane >> 4;

  f32x4 acc[4][2] = {};

  const int ar = t >> 2, ac = (t & 3) * 8;
  const u16* gA = A + (size_t)(m0 + ar) * K + ac;
  const u16* gB = BT + (size_t)(n0 + ar) * K + ac;

#define STAGE1(buf, k0)                                              \
  do {                                                               \
    async16(gA + (k0),                       &As[buf][0][t * 8]);    \
    async16(gA + (k0) + (size_t)64 * K,      &As[buf][0][t * 8 + 2048]); \
    async16(gA + (k0) + 32,                  &As[buf][1][t * 8]);    \
    async16(gA + (k0) + 32 + (size_t)64 * K, &As[buf][1][t * 8 + 2048]); \
    async16(gB + (k0),                       &Bs[buf][0][t * 8]);    \
    async16(gB + (k0) + 32,                  &Bs[buf][1][t * 8]);    \
  } while (0)

  STAGE1(0, 0);
  __syncthreads();
  int p = 0;
  for (int k0 = 0; k0 < K; k0 += 64) {
    if (k0 + 64 < K) STAGE1(p ^ 1, k0 + 64);
#pragma unroll
    for (int kk = 0; kk < 2; kk++) {
      bf16x8 af[4], bfr[2];
#pragma unroll
      for (int i = 0; i < 4; i++)
        af[i] = *(const bf16x8*)&As[p][kk][(wm + i * 16 + lrow) * 32 + quad * 8];
#pragma unroll
      for (int j = 0; j < 2; j++)
        bfr[j] = *(const bf16x8*)&Bs[p][kk][(wn + j * 16 + lrow) * 32 + quad * 8];
#pragma unroll
      for (int i = 0; i < 4; i++)
#pragma unroll
        for (int j = 0; j < 2; j++)
          acc[i][j] = __builtin_amdgcn_mfma_f32_16x16x32_bf16(af[i], bfr[j], acc[i][j], 0, 0, 0);
    }
    __syncthreads();                  // drains async(p^1) + guards buf reuse
    p ^= 1;
  }

  // ---- epilogue: write w tile + masked-transposed Vt tile ----
  // T[d][j] in reused LDS, stride 136 u16 (272B, 16B-aligned rows)
  u16* T = &As[0][0][0];              // 64*136 u16 = 17.4 KB (fits 32 KB)
#pragma unroll
  for (int i = 0; i < 4; i++) {
    int4 mk = *(const int4*)&mask[m0 + wm + i * 16 + quad * 4];
    int mkk[4] = {mk.x, mk.y, mk.z, mk.w};
#pragma unroll
    for (int j2 = 0; j2 < 2; j2++) {
      union { u16 s[4]; double d; } pk;
#pragma unroll
      for (int r = 0; r < 4; r++) {
        int row = wm + i * 16 + quad * 4 + r;
        u16 v = f2bf(acc[i][j2][r]);
        w[(size_t)(m0 + row) * N + n0 + wn + j2 * 16 + lrow] = v;
        pk.s[r] = mkk[r] ? (u16)0 : v;
      }
      int col = wn + j2 * 16 + lrow;
      *(double*)&T[col * 136 + wm + i * 16 + quad * 4] = pk.d;
    }
  }
  __syncthreads();
  // coalesced Vt writes: thread t -> d = t/4, 32 cols at (t%4)*32
  {
    const int bq = m0 >> 11, jl0 = m0 & 2047, h = n0 >> 6;
    u16* vt = Vt + ((size_t)(bq * 16 + h) * 64) * 2048 + jl0;
    const int dd = t >> 2, cc = (t & 3) * 32;
#pragma unroll
    for (int c = 0; c < 4; c++) {
      uint4 q = *(const uint4*)&T[dd * 136 + cc + c * 8];
      *(uint4*)&vt[(size_t)dd * 2048 + cc + c * 8] = q;
    }
  }
#undef STAGE1
}

// ---------------- GEMM2: out = y * WoutT^T + bout (fp32 out) --------------
__launch_bounds__(256)
__global__ void gemm2(const u16* __restrict__ A, const u16* __restrict__ BT,
                      float* __restrict__ C, const float* __restrict__ bias) {
  const int K = 1024, N = 1024;
  __shared__ __align__(16) u16 As[2][2][128 * 32];
  __shared__ __align__(16) u16 Bs[2][2][64 * 32];
  const int t = threadIdx.x;
  const int lane = t & 63, wave = t >> 6;
  const int m0 = blockIdx.x * 128, n0 = blockIdx.y * 64;
  const int wm = (wave & 1) * 64, wn = (wave >> 1) * 32;
  const int lrow = lane & 15, quad = lane >> 4;

  f32x4 acc[4][2] = {};

  const int ar = t >> 2, ac = (t & 3) * 8;
  const u16* gA = A + (size_t)(m0 + ar) * K + ac;
  const u16* gB = BT + (size_t)(n0 + ar) * K + ac;

#define STAGE2(buf, k0)                                              \
  do {                                                               \
    async16(gA + (k0),                       &As[buf][0][t * 8]);    \
    async16(gA + (k0) + (size_t)64 * K,      &As[buf][0][t * 8 + 2048]); \
    async16(gA + (k0) + 32,                  &As[buf][1][t * 8]);    \
    async16(gA + (k0) + 32 + (size_t)64 * K, &As[buf][1][t * 8 + 2048]); \
    async16(gB + (k0),                       &Bs[buf][0][t * 8]);    \
    async16(gB + (k0) + 32,                  &Bs[buf][1][t * 8]);    \
  } while (0)

  STAGE2(0, 0);
  __syncthreads();
  int p = 0;
  for (int k0 = 0; k0 < K; k0 += 64) {
    if (k0 + 64 < K) STAGE2(p ^ 1, k0 + 64);
#pragma unroll
    for (int kk = 0; kk < 2; kk++) {
      bf16x8 af[4], bfr[2];
#pragma unroll
      for (int i = 0; i < 4; i++)
        af[i] = *(const bf16x8*)&As[p][kk][(wm + i * 16 + lrow) * 32 + quad * 8];
#pragma unroll
      for (int j = 0; j < 2; j++)
        bfr[j] = *(const bf16x8*)&Bs[p][kk][(wn + j * 16 + lrow) * 32 + quad * 8];
#pragma unroll
      for (int i = 0; i < 4; i++)
#pragma unroll
        for (int j = 0; j < 2; j++)
          acc[i][j] = __builtin_amdgcn_mfma_f32_16x16x32_bf16(af[i], bfr[j], acc[i][j], 0, 0, 0);
    }
    __syncthreads();
    p ^= 1;
  }

  float bv[2];
#pragma unroll
  for (int j = 0; j < 2; j++)
    bv[j] = bias[n0 + wn + j * 16 + lrow];
#pragma unroll
  for (int i = 0; i < 4; i++)
#pragma unroll
    for (int r = 0; r < 4; r++) {
      int row = m0 + wm + i * 16 + quad * 4 + r;
#pragma unroll
      for (int j = 0; j < 2; j++)
        C[(size_t)row * N + n0 + wn + j * 16 + lrow] = acc[i][j][r] + bv[j];
    }
#undef STAGE2
}

// ---------------- fused attention per (b,h), 64 q-rows per block ----------
// (unchanged round-8/10 winner)
#define SV 72
#define C1 0.18033688f      // 0.125 * log2(e)
#define C2 -28.853901f      // -20 * log2(e)
__launch_bounds__(256)
__global__ void attn_kernel(const u16* __restrict__ w, const u16* __restrict__ Vt,
                            u16* __restrict__ y) {
  __shared__ __align__(16) u16 Ws[64 * SV];        // K rows [key][d]
  __shared__ __align__(16) u16 VTs[64 * SV];       // V^T [d][key]
  __shared__ __align__(16) u16 P[4][16 * SV];      // per-wave P: [16 q][64 key]
  const int t = threadIdx.x, lane = t & 63, wave = t >> 6;
  const int lrow = lane & 15, quad = lane >> 4;
  const int bh = blockIdx.y, b = bh >> 4, h = bh & 15;
  const int q0 = blockIdx.x * 64;
  const size_t rowb = (size_t)b * 2048;
  const int hc = h * 64;
  u16* Pw = P[wave];

  const int sr = t >> 2, sc = (t & 3) * 16;
  const u16* kg = &w[(rowb + sr) * 1024 + hc + sc];
  const u16* vg = &Vt[((size_t)bh * 64 + sr) * 2048 + sc];

  bf16x8 qf0, qf1;
  {
    const size_t qrow = rowb + q0 + wave * 16 + lrow;
    qf0 = *(const bf16x8*)&w[qrow * 1024 + hc + quad * 8];
    qf1 = *(const bf16x8*)&w[qrow * 1024 + hc + 32 + quad * 8];
  }

  uint4 ka = *(const uint4*)kg, kb = *(const uint4*)(kg + 8);
  uint4 va = *(const uint4*)vg, vc = *(const uint4*)(vg + 8);

  f32x4 o[4] = {};
  float lrun[4] = {0.f, 0.f, 0.f, 0.f};

  for (int j0 = 0; j0 < 2048; j0 += 64) {
    __syncthreads();
    *(uint4*)&Ws[sr * SV + sc]      = ka;
    *(uint4*)&Ws[sr * SV + sc + 8]  = kb;
    *(uint4*)&VTs[sr * SV + sc]     = va;
    *(uint4*)&VTs[sr * SV + sc + 8] = vc;
    __syncthreads();

    if (j0 + 64 < 2048) {
      const u16* kn = kg + (size_t)(j0 + 64) * 1024;
      const u16* vn = vg + j0 + 64;
      ka = *(const uint4*)kn; kb = *(const uint4*)(kn + 8);
      va = *(const uint4*)vn; vc = *(const uint4*)(vn + 8);
    }

    f32x4 st[4];
#pragma unroll
    for (int jt = 0; jt < 4; jt++) {
      bf16x8 kf0 = *(const bf16x8*)&Ws[(jt * 16 + lrow) * SV + quad * 8];
      bf16x8 kf1 = *(const bf16x8*)&Ws[(jt * 16 + lrow) * SV + 32 + quad * 8];
      f32x4 z = {};
      z = __builtin_amdgcn_mfma_f32_16x16x32_bf16(qf0, kf0, z, 0, 0, 0);
      z = __builtin_amdgcn_mfma_f32_16x16x32_bf16(qf1, kf1, z, 0, 0, 0);
      st[jt] = z;
    }

#pragma unroll
    for (int jt = 0; jt < 4; jt++) {
#pragma unroll
      for (int r = 0; r < 4; r++) {
        float e = exp2f(fmaf(st[jt][r], C1, C2));
        lrun[r] += e;                           // denominator: UNmasked
        Pw[(quad * 4 + r) * SV + jt * 16 + lrow] = f2bf(e);
      }
    }

    bf16x8 pa0 = *(const bf16x8*)&Pw[lrow * SV + quad * 8];
    bf16x8 pa1 = *(const bf16x8*)&Pw[lrow * SV + 32 + quad * 8];
#pragma unroll
    for (int dt = 0; dt < 4; dt++) {
      bf16x8 vb0 = *(const bf16x8*)&VTs[(dt * 16 + lrow) * SV + quad * 8];
      bf16x8 vb1 = *(const bf16x8*)&VTs[(dt * 16 + lrow) * SV + 32 + quad * 8];
      o[dt] = __builtin_amdgcn_mfma_f32_16x16x32_bf16(pa0, vb0, o[dt], 0, 0, 0);
      o[dt] = __builtin_amdgcn_mfma_f32_16x16x32_bf16(pa1, vb1, o[dt], 0, 0, 0);
    }
  }

#pragma unroll
  for (int r = 0; r < 4; r++) {
    float l = lrun[r];
#pragma unroll
    for (int s = 8; s >= 1; s >>= 1)
      l += __shfl_xor(l, s, 64);
    float inv = 1.f / l;
    const size_t orow = rowb + q0 + wave * 16 + quad * 4 + r;
#pragma unroll
    for (int dt = 0; dt < 4; dt++)
      y[orow * 1024 + hc + dt * 16 + lrow] = f2bf(o[dt][r] * inv);
  }
}

// --------------------------------------------------------------------------
extern "C" void kernel_launch(void* const* d_in, const int* in_sizes, int n_in,
                              void* d_out, int out_size, void* d_ws, size_t ws_size,
                              hipStream_t stream) {
  const float* x    = (const float*)d_in[0];  // (2,2048,1024) fp32
  const int* mask   = (const int*)d_in[1];    // (2,2048) int32
  const float* Wqkv = (const float*)d_in[2];  // (1024,1024) fp32
  const float* Wout = (const float*)d_in[3];  // (1024,1024) fp32
  const float* bout = (const float*)d_in[4];  // (1024,) fp32
  float* out = (float*)d_out;                 // (2,2048,1024) fp32

  u16* w     = (u16*)d_ws;                 // 4096*1024 bf16   (8 MB)
  u16* y     = w + 4096 * 1024;            // 4096*1024 bf16   (8 MB)
  u16* WqkvT = y + 4096 * 1024;            // 1024*1024 bf16   (2 MB)
  u16* WoutT = WqkvT + 1024 * 1024;        // 1024*1024 bf16   (2 MB)
  u16* Vt    = WoutT + 1024 * 1024;        // 32*64*2048 bf16  (8 MB)
  u16* xb    = y;                          // alias: y dead until attn writes it

  prep<<<dim3(32, 32, 4), dim3(32, 8), 0, stream>>>(Wqkv, WqkvT, Wout, WoutT, x, xb);
  gemm1_fused<<<dim3(32, 16), 256, 0, stream>>>(xb, WqkvT, w, mask, Vt);
  attn_kernel<<<dim3(32, 32), 256, 0, stream>>>(w, Vt, y);
  gemm2<<<dim3(32, 16), 256, 0, stream>>>(y, WoutT, out, bout);
}